// Round 7
// baseline (63.795 us; speedup 1.0000x reference)
//
#include <hip/hip_runtime.h>

// GraphConsis fused encoder + dot — round 6 (round-5 with compile fix).
// B=4096, H=50, A=32, L=82, D=64, tables 100000x64 f32.
//
// Model (fits R1-R4): per-CU L1 miss-concurrency (MSHR ~16 lines) x latency
// ~700cy caps scattered-gather throughput at ~1.5 B/cy/CU -> f32 rows
// (4 lines) ~55us, f16 rows (2 lines) ~28us. Only line count and latency
// matter; software MLP and instruction count are secondary.
//
//  - f16 tables (absmax 0.016, 4.7x inside threshold)
//  - ONE fused conversion kernel, non-temporal f32 source reads via native
//    clang vector type (HIP float4 is a struct -> rejected by the builtin)
//  - rlog computed per-wave in-register (no setup dispatch, no barrier)
//  - prefetch-all with __launch_bounds__(256,2)
//  - f32 fallback (round-4 proven) if ws_size too small

typedef _Float16 half4v __attribute__((ext_vector_type(4)));
typedef float f32x4 __attribute__((ext_vector_type(4)));

#define NB 4096
#define NH 50
#define NA 32
#define ND 64
#define NROWS 100000

// ---------------- conversion: both tables, NT source reads ----------------

__global__ __launch_bounds__(256) void convert_f16_both(
    const float* __restrict__ u2e, const float* __restrict__ v2e,
    _Float16* __restrict__ uh, _Float16* __restrict__ vh, int n4_per)
{
    int i = blockIdx.x * blockDim.x + threadIdx.x;
    const int stride = gridDim.x * blockDim.x;
    const f32x4* su = (const f32x4*)u2e;
    const f32x4* sv = (const f32x4*)v2e;
    half4v* du = (half4v*)uh;
    half4v* dv = (half4v*)vh;
    for (; i < 2 * n4_per; i += stride) {
        const bool second = (i >= n4_per);
        const f32x4* s = second ? sv : su;
        half4v* d = second ? dv : du;
        const int k = second ? (i - n4_per) : i;
        const f32x4 v = __builtin_nontemporal_load(&s[k]);
        half4v h;
        h.x = (_Float16)v.x; h.y = (_Float16)v.y;
        h.z = (_Float16)v.z; h.w = (_Float16)v.w;
        d[k] = h;
    }
}

// ---------------- main kernel, f16 gather path ----------------

__global__ __launch_bounds__(256, 2) void graphconsis_f16(
    const float* __restrict__ u2e, const float* __restrict__ v2e,
    const _Float16* __restrict__ uh, const _Float16* __restrict__ vh,
    const float* __restrict__ r2e, const float* __restrict__ ra,
    const float* __restrict__ lin1_W, const float* __restrict__ lin1_b,
    const int* __restrict__ nodes_u, const int* __restrict__ nodes_v,
    const int* __restrict__ hist_u, const int* __restrict__ hist_ur,
    const int* __restrict__ adj_u,
    const int* __restrict__ hist_v, const int* __restrict__ hist_vr,
    const int* __restrict__ adj_v,
    float* __restrict__ out)
{
    __shared__ float lds_comb[4][128];
    __shared__ float ed[4][64];

    const int wid  = threadIdx.x >> 6;
    const int lane = threadIdx.x & 63;
    const int g    = lane >> 4;          // entry subgroup 0..3
    const int j    = lane & 15;          // dim-quad index
    const int side = wid >> 1;           // 0 = user, 1 = item
    const int b    = __builtin_amdgcn_readfirstlane(blockIdx.x * 2 + (wid & 1));

    const float* nodeTab     = side ? v2e : u2e;
    const _Float16* histTab  = side ? uh : vh;
    const _Float16* neighTab = side ? vh : uh;
    const int* nodes = side ? nodes_v : nodes_u;
    const int* hn    = side ? hist_v  : hist_u;
    const int* hr    = side ? hist_vr : hist_ur;
    const int* adj   = side ? adj_v   : adj_u;

    const float4 ra4 = *(const float4*)(ra + 4 * j);

    // ---- index preload (entry 4k+g at iteration k) ----
    int hidx[13];
    #pragma unroll
    for (int k = 0; k < 13; ++k) {
        int l = 4 * k + g; if (l > NH - 1) l = NH - 1;
        hidx[k] = hn[b * NH + l];
    }
    int aidx[8];
    #pragma unroll
    for (int k = 0; k < 8; ++k)
        aidx[k] = adj[b * NA + 4 * k + g];
    int hrv = 6;   // rate index for history entry 4j+g (6 also covers masked)
    { int l = 4 * j + g; if (l < NH) hrv = hr[b * NH + l]; }

    // ---- prefetch ALL embedding rows into registers ----
    const float4 nf4 = *(const float4*)(nodeTab + nodes[b] * ND + 4 * j);
    half4v rh[13];
    #pragma unroll
    for (int k = 0; k < 13; ++k)
        rh[k] = *(const half4v*)(histTab + hidx[k] * ND + 4 * j);
    half4v raj[8];
    #pragma unroll
    for (int k = 0; k < 8; ++k)
        raj[k] = *(const half4v*)(neighTab + aidx[k] * ND + 4 * j);

    // ---- per-wave rate logits (in-register, no barrier; overlaps gathers) ----
    const float ra_hi = ra[64 + lane];
    float r0, r1, r2, r3, r4, r5, r6;
    {
        float t[7];
        #pragma unroll
        for (int r = 0; r < 7; ++r) {
            float part = r2e[r * 64 + lane] * ra_hi;
            part += __shfl_xor(part, 1);
            part += __shfl_xor(part, 2);
            part += __shfl_xor(part, 4);
            part += __shfl_xor(part, 8);
            part += __shfl_xor(part, 16);
            part += __shfl_xor(part, 32);
            t[r] = part;
        }
        r0 = t[0]; r1 = t[1]; r2 = t[2]; r3 = t[3]; r4 = t[4]; r5 = t[5]; r6 = t[6];
    }
    float rl0 = r6;                       // hrv==6 or masked
    rl0 = (hrv == 0) ? r0 : rl0;
    rl0 = (hrv == 1) ? r1 : rl0;
    rl0 = (hrv == 2) ? r2 : rl0;
    rl0 = (hrv == 3) ? r3 : rl0;
    rl0 = (hrv == 4) ? r4 : rl0;
    rl0 = (hrv == 5) ? r5 : rl0;
    const float rlog6 = r6;

    float ssum = 0.f;
    float4 acc = make_float4(0.f, 0.f, 0.f, 0.f);

    // ---- history entries 0..47 ----
    #pragma unroll
    for (int k = 0; k < 12; ++k) {
        const half4v eh = rh[k];
        const float4 e = make_float4((float)eh.x, (float)eh.y, (float)eh.z, (float)eh.w);
        float part = e.x * ra4.x;
        part = fmaf(e.y, ra4.y, part);
        part = fmaf(e.z, ra4.z, part);
        part = fmaf(e.w, ra4.w, part);
        part += (j == k) ? rl0 : 0.f;
        part += __shfl_xor(part, 1);
        part += __shfl_xor(part, 2);
        part += __shfl_xor(part, 4);
        part += __shfl_xor(part, 8);
        const float p = __expf(part);
        ssum += p;
        acc.x = fmaf(p, e.x, acc.x);
        acc.y = fmaf(p, e.y, acc.y);
        acc.z = fmaf(p, e.z, acc.z);
        acc.w = fmaf(p, e.w, acc.w);
    }
    // ---- history tail: entries 48,49 live on groups 0,1 ----
    {
        const half4v eh = rh[12];
        const float4 e = make_float4((float)eh.x, (float)eh.y, (float)eh.z, (float)eh.w);
        float part = e.x * ra4.x;
        part = fmaf(e.y, ra4.y, part);
        part = fmaf(e.z, ra4.z, part);
        part = fmaf(e.w, ra4.w, part);
        part += (j == 12) ? rl0 : 0.f;
        part += __shfl_xor(part, 1);
        part += __shfl_xor(part, 2);
        part += __shfl_xor(part, 4);
        part += __shfl_xor(part, 8);
        const float p = (g < 2) ? __expf(part) : 0.f;
        ssum += p;
        acc.x = fmaf(p, e.x, acc.x);
        acc.y = fmaf(p, e.y, acc.y);
        acc.z = fmaf(p, e.z, acc.z);
        acc.w = fmaf(p, e.w, acc.w);
    }
    // ---- adj entries 0..31 (rate logit = rlog6) ----
    #pragma unroll
    for (int k = 0; k < 8; ++k) {
        const half4v eh = raj[k];
        const float4 e = make_float4((float)eh.x, (float)eh.y, (float)eh.z, (float)eh.w);
        float part = e.x * ra4.x;
        part = fmaf(e.y, ra4.y, part);
        part = fmaf(e.z, ra4.z, part);
        part = fmaf(e.w, ra4.w, part);
        part += __shfl_xor(part, 1);
        part += __shfl_xor(part, 2);
        part += __shfl_xor(part, 4);
        part += __shfl_xor(part, 8);
        const float p = __expf(part + rlog6);
        ssum += p;
        acc.x = fmaf(p, e.x, acc.x);
        acc.y = fmaf(p, e.y, acc.y);
        acc.z = fmaf(p, e.z, acc.z);
        acc.w = fmaf(p, e.w, acc.w);
    }

    // combine the 4 entry-groups
    ssum += __shfl_xor(ssum, 16);
    ssum += __shfl_xor(ssum, 32);
    acc.x += __shfl_xor(acc.x, 16); acc.x += __shfl_xor(acc.x, 32);
    acc.y += __shfl_xor(acc.y, 16); acc.y += __shfl_xor(acc.y, 32);
    acc.z += __shfl_xor(acc.z, 16); acc.z += __shfl_xor(acc.z, 32);
    acc.w += __shfl_xor(acc.w, 16); acc.w += __shfl_xor(acc.w, 32);

    const float inv = 1.0f / ssum;

    // comb -> own LDS slice (wave-local, wave-synchronous: no barrier)
    if (g == 0) {
        *(float4*)&lds_comb[wid][4 * j] = nf4;
        float4 n4 = make_float4(acc.x * inv, acc.y * inv, acc.z * inv, acc.w * inv);
        *(float4*)&lds_comb[wid][64 + 4 * j] = n4;
    }

    // out_j = relu(b_j + sum_k W[j][k] * comb[k]); lane = output j
    float o = lin1_b[lane];
    const float4* W4 = (const float4*)(lin1_W + lane * 128);
    const float4* C4 = (const float4*)lds_comb[wid];
    #pragma unroll 8
    for (int kk = 0; kk < 32; ++kk) {
        const float4 w = W4[kk];
        const float4 c = C4[kk];
        o = fmaf(w.x, c.x, o);
        o = fmaf(w.y, c.y, o);
        o = fmaf(w.z, c.z, o);
        o = fmaf(w.w, c.w, o);
    }
    const float evec = fmaxf(o, 0.f);

    ed[wid][lane] = evec;
    __syncthreads();

    if (wid < 2) {
        float prod = ed[wid][lane] * ed[wid + 2][lane];
        #pragma unroll
        for (int off = 32; off >= 1; off >>= 1)
            prod += __shfl_xor(prod, off);
        if (lane == 0) out[blockIdx.x * 2 + wid] = prod;
    }
}

// ---------------- fallback f32 main kernel (round-4 proven) ----------------

__global__ __launch_bounds__(256) void graphconsis_f32(
    const float* __restrict__ u2e, const float* __restrict__ v2e,
    const float* __restrict__ r2e, const float* __restrict__ ra,
    const float* __restrict__ lin1_W, const float* __restrict__ lin1_b,
    const int* __restrict__ nodes_u, const int* __restrict__ nodes_v,
    const int* __restrict__ hist_u, const int* __restrict__ hist_ur,
    const int* __restrict__ adj_u,
    const int* __restrict__ hist_v, const int* __restrict__ hist_vr,
    const int* __restrict__ adj_v,
    float* __restrict__ out)
{
    __shared__ float rlog_lds[8];
    __shared__ float lds_comb[4][128];
    __shared__ float ed[4][64];

    const int wid  = threadIdx.x >> 6;
    const int lane = threadIdx.x & 63;
    const int g    = lane >> 4;
    const int j    = lane & 15;
    const int side = wid >> 1;
    const int b    = __builtin_amdgcn_readfirstlane(blockIdx.x * 2 + (wid & 1));

    const float* nodeTab  = side ? v2e : u2e;
    const float* histTab  = side ? u2e : v2e;
    const float* neighTab = side ? v2e : u2e;
    const int* nodes = side ? nodes_v : nodes_u;
    const int* hn    = side ? hist_v  : hist_u;
    const int* hr    = side ? hist_vr : hist_ur;
    const int* adj   = side ? adj_v   : adj_u;

    const float4 ra4 = *(const float4*)(ra + 4 * j);

    int hidx[13];
    #pragma unroll
    for (int k = 0; k < 13; ++k) {
        int l = 4 * k + g; if (l > NH - 1) l = NH - 1;
        hidx[k] = hn[b * NH + l];
    }
    int aidx[8];
    #pragma unroll
    for (int k = 0; k < 8; ++k)
        aidx[k] = adj[b * NA + 4 * k + g];
    int hrv = 7;
    { int l = 4 * j + g; if (l < NH) hrv = hr[b * NH + l]; }

    const float4 nf4 = *(const float4*)(nodeTab + nodes[b] * ND + 4 * j);
    float4 rh[13];
    #pragma unroll
    for (int k = 0; k < 13; ++k)
        rh[k] = *(const float4*)(histTab + hidx[k] * ND + 4 * j);
    float4 raj[8];
    #pragma unroll
    for (int k = 0; k < 8; ++k)
        raj[k] = *(const float4*)(neighTab + aidx[k] * ND + 4 * j);

    if (wid == 0) {
        const float ra_hi = ra[64 + lane];
        #pragma unroll
        for (int r = 0; r < 7; ++r) {
            float part = r2e[r * 64 + lane] * ra_hi;
            #pragma unroll
            for (int off = 32; off >= 1; off >>= 1)
                part += __shfl_xor(part, off);
            if (lane == 0) rlog_lds[r] = part;
        }
        if (lane == 0) rlog_lds[7] = 0.f;
    }
    __syncthreads();

    const float rl0   = rlog_lds[hrv];
    const float rlog6 = rlog_lds[6];

    float ssum = 0.f;
    float4 acc = make_float4(0.f, 0.f, 0.f, 0.f);

    #pragma unroll
    for (int k = 0; k < 12; ++k) {
        const float4 e = rh[k];
        float part = e.x * ra4.x;
        part = fmaf(e.y, ra4.y, part);
        part = fmaf(e.z, ra4.z, part);
        part = fmaf(e.w, ra4.w, part);
        part += (j == k) ? rl0 : 0.f;
        part += __shfl_xor(part, 1);
        part += __shfl_xor(part, 2);
        part += __shfl_xor(part, 4);
        part += __shfl_xor(part, 8);
        const float p = __expf(part);
        ssum += p;
        acc.x = fmaf(p, e.x, acc.x);
        acc.y = fmaf(p, e.y, acc.y);
        acc.z = fmaf(p, e.z, acc.z);
        acc.w = fmaf(p, e.w, acc.w);
    }
    {
        const float4 e = rh[12];
        float part = e.x * ra4.x;
        part = fmaf(e.y, ra4.y, part);
        part = fmaf(e.z, ra4.z, part);
        part = fmaf(e.w, ra4.w, part);
        part += (j == 12) ? rl0 : 0.f;
        part += __shfl_xor(part, 1);
        part += __shfl_xor(part, 2);
        part += __shfl_xor(part, 4);
        part += __shfl_xor(part, 8);
        const float p = (g < 2) ? __expf(part) : 0.f;
        ssum += p;
        acc.x = fmaf(p, e.x, acc.x);
        acc.y = fmaf(p, e.y, acc.y);
        acc.z = fmaf(p, e.z, acc.z);
        acc.w = fmaf(p, e.w, acc.w);
    }
    #pragma unroll
    for (int k = 0; k < 8; ++k) {
        const float4 e = raj[k];
        float part = e.x * ra4.x;
        part = fmaf(e.y, ra4.y, part);
        part = fmaf(e.z, ra4.z, part);
        part = fmaf(e.w, ra4.w, part);
        part += __shfl_xor(part, 1);
        part += __shfl_xor(part, 2);
        part += __shfl_xor(part, 4);
        part += __shfl_xor(part, 8);
        const float p = __expf(part + rlog6);
        ssum += p;
        acc.x = fmaf(p, e.x, acc.x);
        acc.y = fmaf(p, e.y, acc.y);
        acc.z = fmaf(p, e.z, acc.z);
        acc.w = fmaf(p, e.w, acc.w);
    }

    ssum += __shfl_xor(ssum, 16);
    ssum += __shfl_xor(ssum, 32);
    acc.x += __shfl_xor(acc.x, 16); acc.x += __shfl_xor(acc.x, 32);
    acc.y += __shfl_xor(acc.y, 16); acc.y += __shfl_xor(acc.y, 32);
    acc.z += __shfl_xor(acc.z, 16); acc.z += __shfl_xor(acc.z, 32);
    acc.w += __shfl_xor(acc.w, 16); acc.w += __shfl_xor(acc.w, 32);

    const float inv = 1.0f / ssum;

    if (g == 0) {
        *(float4*)&lds_comb[wid][4 * j] = nf4;
        float4 n4 = make_float4(acc.x * inv, acc.y * inv, acc.z * inv, acc.w * inv);
        *(float4*)&lds_comb[wid][64 + 4 * j] = n4;
    }

    float o = lin1_b[lane];
    const float4* W4 = (const float4*)(lin1_W + lane * 128);
    const float4* C4 = (const float4*)lds_comb[wid];
    #pragma unroll 8
    for (int kk = 0; kk < 32; ++kk) {
        const float4 w = W4[kk];
        const float4 c = C4[kk];
        o = fmaf(w.x, c.x, o);
        o = fmaf(w.y, c.y, o);
        o = fmaf(w.z, c.z, o);
        o = fmaf(w.w, c.w, o);
    }
    const float evec = fmaxf(o, 0.f);

    ed[wid][lane] = evec;
    __syncthreads();

    if (wid < 2) {
        float prod = ed[wid][lane] * ed[wid + 2][lane];
        #pragma unroll
        for (int off = 32; off >= 1; off >>= 1)
            prod += __shfl_xor(prod, off);
        if (lane == 0) out[blockIdx.x * 2 + wid] = prod;
    }
}

// ---------------- launch ----------------

extern "C" void kernel_launch(void* const* d_in, const int* in_sizes, int n_in,
                              void* d_out, int out_size, void* d_ws, size_t ws_size,
                              hipStream_t stream)
{
    const float* u2e     = (const float*)d_in[0];
    const float* v2e     = (const float*)d_in[1];
    const float* r2e     = (const float*)d_in[2];
    const float* ra      = (const float*)d_in[3];
    // d_in[4] agg_W, d_in[5] agg_b: dead code in the reference
    const float* lin1_W  = (const float*)d_in[6];
    const float* lin1_b  = (const float*)d_in[7];
    const int* nodes_u   = (const int*)d_in[8];
    const int* nodes_v   = (const int*)d_in[9];
    const int* hist_u    = (const int*)d_in[10];
    const int* hist_ur   = (const int*)d_in[11];
    const int* adj_u     = (const int*)d_in[12];
    const int* hist_v    = (const int*)d_in[13];
    const int* hist_vr   = (const int*)d_in[14];
    const int* adj_v     = (const int*)d_in[15];
    float* out = (float*)d_out;

    const size_t tab_elems = (size_t)NROWS * ND;           // 6.4M
    const size_t f16_bytes = tab_elems * sizeof(_Float16); // 12.8MB per table
    const size_t need = 2 * f16_bytes;

    if (ws_size >= need) {
        _Float16* uh = (_Float16*)d_ws;
        _Float16* vh = (_Float16*)((char*)d_ws + f16_bytes);
        const int n4_per = (int)(tab_elems / 4);
        hipLaunchKernelGGL(convert_f16_both, dim3(4096), dim3(256), 0, stream,
                           u2e, v2e, uh, vh, n4_per);
        hipLaunchKernelGGL(graphconsis_f16, dim3(NB / 2), dim3(256), 0, stream,
                           u2e, v2e, uh, vh, r2e, ra, lin1_W, lin1_b,
                           nodes_u, nodes_v, hist_u, hist_ur, adj_u,
                           hist_v, hist_vr, adj_v, out);
    } else {
        hipLaunchKernelGGL(graphconsis_f32, dim3(NB / 2), dim3(256), 0, stream,
                           u2e, v2e, r2e, ra, lin1_W, lin1_b,
                           nodes_u, nodes_v, hist_u, hist_ur, adj_u,
                           hist_v, hist_vr, adj_v, out);
    }
}